// Round 8
// baseline (711.277 us; speedup 1.0000x reference)
//
#include <hip/hip_runtime.h>

// ---------------------------------------------------------------------------
// SwinTransformerBlock, MI355X / gfx950. fp32 I/O, bf16 MFMA core.
// wprep -> padfill -> gather -> fused_fast (per 7x7 window) -> scatter.
// Round 8: fallback-free fast kernel (all weight loads b128 from wsT; no
//   dual-path bload => no worst-path register pressure). LDS 27136 B
//   (Q in regs via M-split+xp; t2 parked in LDS). Barriers 13 -> 6.
//   r5 kernel kept verbatim as swin_fused_safe for tiny-ws fallback.
// ---------------------------------------------------------------------------

typedef __bf16 bf16;
typedef __attribute__((ext_vector_type(8))) __bf16 bf16x8;
typedef __attribute__((ext_vector_type(4))) __bf16 bf16x4;
typedef __attribute__((ext_vector_type(4))) float f32x4;
typedef __attribute__((ext_vector_type(4))) int i32x4;
typedef __attribute__((ext_vector_type(2))) int i32x2;

#define LDA 104      // row stride (elems) for [64][*] LDS tiles
#define LDV 72       // row stride for V^T [96][*]
#define LDW 233      // gather/scatter transpose-tile stride
#define TOKW 6144    // 64*96 elems per window

union U8 { int i[4]; bf16x8 v; };

__device__ __forceinline__ f32x4 mfma16(bf16x8 a, bf16x8 b, f32x4 c) {
    return __builtin_amdgcn_mfma_f32_16x16x32_bf16(a, b, c, 0, 0, 0);
}
__device__ __forceinline__ int pkbf(float lo, float hi) {
    int r; asm("v_cvt_pk_bf16_f32 %0, %1, %2" : "=v"(r) : "v"(lo), "v"(hi)); return r;
}
__device__ __forceinline__ float rcpf(float x) {
    float r; asm("v_rcp_f32 %0, %1" : "=v"(r) : "v"(x)); return r;
}
__device__ __forceinline__ float gelu_f(float v) {
    const float a = -2.30220770f, b = -0.10294852f;
    float e = exp2f(v * __builtin_fmaf(b, v * v, a));
    return v * rcpf(1.f + e);
}
__device__ __forceinline__ float bf2f(int dw, int hi) {
    union { int i; float f; } u;
    u.i = hi ? (dw & 0xffff0000) : (dw << 16);
    return u.f;
}

// 16x32 C-tile -> fragment transpose (verified r3-r7).
__device__ __forceinline__ bf16x8 xp(int p0, int p1, int q0, int q1,
                                     int addr0, int addr1, bool hi5) {
    U8 w;
    int a0 = __builtin_amdgcn_ds_bpermute(addr0, p0);
    int b0 = __builtin_amdgcn_ds_bpermute(addr0, q0);
    w.i[0] = hi5 ? b0 : a0;
    int a1 = __builtin_amdgcn_ds_bpermute(addr0, p1);
    int b1 = __builtin_amdgcn_ds_bpermute(addr0, q1);
    w.i[1] = hi5 ? b1 : a1;
    int a2 = __builtin_amdgcn_ds_bpermute(addr1, p0);
    int b2 = __builtin_amdgcn_ds_bpermute(addr1, q0);
    w.i[2] = hi5 ? b2 : a2;
    int a3 = __builtin_amdgcn_ds_bpermute(addr1, p1);
    int b3 = __builtin_amdgcn_ds_bpermute(addr1, q1);
    w.i[3] = hi5 ? b3 : a3;
    return w.v;
}

// ---------------- weight pre-transpose (fp32 -> bf16 [N][K]) ---------------
__global__ void swin_wprep(const float* __restrict__ qkv_w,
                           const float* __restrict__ proj_w,
                           const float* __restrict__ fc1_w,
                           const float* __restrict__ fc2_w,
                           bf16* __restrict__ wsT) {
    int i = blockIdx.x * 256 + threadIdx.x;
    if (i < 27648) { int n = i / 96, k = i - n * 96; wsT[i] = (bf16)qkv_w[k * 288 + n]; }
    else if (i < 36864) { int j = i - 27648, n = j / 96, k = j - n * 96; wsT[i] = (bf16)proj_w[k * 96 + n]; }
    else if (i < 73728) { int j = i - 36864, n = j / 96, k = j - n * 96; wsT[i] = (bf16)fc1_w[k * 384 + n]; }
    else if (i < 110592){ int j = i - 73728, n = j / 384, k = j - n * 384; wsT[i] = (bf16)fc2_w[k * 96 + n]; }
}

// ---------------- K0: zero pad rows 49..63 of every window -----------------
__global__ void swin_padfill(bf16* __restrict__ tokW) {
    int id = blockIdx.x * 256 + threadIdx.x;
    int win = id / 180, r = id - win * 180;
    int row = 49 + r / 12, c8 = r - (r / 12) * 12;
    *(i32x4*)(tokW + (size_t)win * TOKW + row * 96 + c8 * 8) = i32x4{0, 0, 0, 0};
}

// ---------------- K1: x[B,C,H,W] fp32 -> tokW[win][64][96] bf16 ------------
__global__ __launch_bounds__(256)
void swin_gather(const float* __restrict__ x, bf16* __restrict__ tokW) {
    __shared__ bf16 sT[96 * LDW];
    const int tid = threadIdx.x;
    const int bi = blockIdx.x;
    const int b = bi / 224, h = bi - b * 224;
    const int wy = h / 7, ty = h - wy * 7;
    const size_t xbase = (size_t)b * 4816896 + (size_t)h * 224;

#pragma unroll
    for (int i = 0; i < 21; ++i) {
        int id = i * 256 + tid;
        int c = id / 56, w4 = id - c * 56;
        f32x4 v = *(const f32x4*)(x + xbase + (size_t)c * 50176 + w4 * 4);
#pragma unroll
        for (int j = 0; j < 4; ++j) sT[c * LDW + w4 * 4 + j] = (bf16)v[j];
    }
    __syncthreads();

#pragma unroll
    for (int i = 0; i < 11; ++i) {
        int id = i * 256 + tid;
        if (id < 2688) {
            int win = id / 84, r = id - win * 84;
            int tx = r / 12, c8 = r - tx * 12;
            bf16x8 v;
#pragma unroll
            for (int j = 0; j < 8; ++j) v[j] = sT[(c8 * 8 + j) * LDW + win * 7 + tx];
            *(i32x4*)(tokW + (size_t)(b * 1024 + wy * 32 + win) * TOKW
                      + (ty * 7 + tx) * 96 + c8 * 8) = *(i32x4*)&v;
        }
    }
}

// ---------------- K3: tokW -> out[B,C,H,W] fp32 ----------------------------
__global__ __launch_bounds__(256)
void swin_scatter(const bf16* __restrict__ tokW, float* __restrict__ out) {
    __shared__ bf16 sT[96 * LDW];
    const int tid = threadIdx.x;
    const int bi = blockIdx.x;
    const int b = bi / 224, h = bi - b * 224;
    const int wy = h / 7, ty = h - wy * 7;
    const size_t obase = (size_t)b * 4816896 + (size_t)h * 224;

#pragma unroll
    for (int i = 0; i < 11; ++i) {
        int id = i * 256 + tid;
        if (id < 2688) {
            int win = id / 84, r = id - win * 84;
            int tx = r / 12, c8 = r - tx * 12;
            bf16x8 v = *(const bf16x8*)(tokW + (size_t)(b * 1024 + wy * 32 + win) * TOKW
                                        + (ty * 7 + tx) * 96 + c8 * 8);
#pragma unroll
            for (int j = 0; j < 8; ++j) sT[(c8 * 8 + j) * LDW + win * 7 + tx] = v[j];
        }
    }
    __syncthreads();

#pragma unroll
    for (int i = 0; i < 21; ++i) {
        int id = i * 256 + tid;
        int c = id / 56, w4 = id - c * 56;
        f32x4 v;
#pragma unroll
        for (int j = 0; j < 4; ++j) v[j] = (float)sT[c * LDW + w4 * 4 + j];
        *(f32x4*)(out + obase + (size_t)c * 50176 + w4 * 4) = v;
    }
}

// =============== K2 FAST: fused block, fallback-free ========================
__global__ __launch_bounds__(256, 4)
void swin_fused_fast(bf16* __restrict__ tokW,
                     const float* __restrict__ n1w, const float* __restrict__ n1b,
                     const float* __restrict__ qkvb, const float* __restrict__ projb,
                     const float* __restrict__ n2w, const float* __restrict__ n2b,
                     const float* __restrict__ fc1b, const float* __restrict__ fc2b,
                     const bf16* __restrict__ wsT) {
    // 27136 B LDS
    __shared__ __attribute__((aligned(16))) bf16 L[13568];
    bf16* RB = L;           // raw -> LN1'd -> K [64][LDA] -> final tokens
    bf16* RV = L + 6656;    // V^T [96][LDV] -> raw t2 [64][LDA]

    const int tid  = threadIdx.x;
    const int wave = tid >> 6;
    const int lane = tid & 63;
    const int g    = lane >> 4;
    const int q16  = lane & 15;

    const int win = blockIdx.x;
    bf16* myWin = tokW + (size_t)win * TOKW;

    const bool hi5 = (lane & 32) != 0;
    const int addr0 = ((lane & 16) << 3) | (q16 << 2);
    const int addr1 = addr0 + 64;

    const bf16* qkvT  = wsT;
    const bf16* projT = wsT + 27648;
    const bf16* fc1T  = wsT + 36864;
    const bf16* fc2T  = wsT + 73728;

    // ---- P0: window -> RB (raw tokens, pad rows pre-zeroed in tokW)
#pragma unroll
    for (int i = 0; i < 3; ++i) {
        int id = i * 256 + tid;
        int row = id / 12, c8 = id - row * 12;
        *(i32x4*)&RB[row * LDA + c8 * 8] = *(const i32x4*)(myWin + row * 96 + c8 * 8);
    }
    __syncthreads();

    // ---- LN1: stats + normalize in place (4 lanes per row)
    {
        int r = tid >> 2, p = tid & 3;
        const int c0 = p * 24;
        bf16* rp = &RB[r * LDA + c0];
        bf16x8 v0 = *(const bf16x8*)rp;
        bf16x8 v1 = *(const bf16x8*)(rp + 8);
        bf16x8 v2 = *(const bf16x8*)(rp + 16);
        float s = 0.f, s2 = 0.f;
#pragma unroll
        for (int j = 0; j < 8; ++j) {
            float a = (float)v0[j], c = (float)v1[j], d = (float)v2[j];
            s += a + c + d; s2 += a * a + c * c + d * d;
        }
        s += __shfl_xor(s, 1);  s2 += __shfl_xor(s2, 1);
        s += __shfl_xor(s, 2);  s2 += __shfl_xor(s2, 2);
        float mu = s * (1.f / 96.f);
        float rs = rsqrtf(fmaxf(s2 * (1.f / 96.f) - mu * mu, 0.f) + 1e-5f);
        bf16x8 o0, o1, o2;
#pragma unroll
        for (int j = 0; j < 8; ++j) {
            o0[j] = (bf16)(((float)v0[j] - mu) * rs * n1w[c0 + j] + n1b[c0 + j]);
            o1[j] = (bf16)(((float)v1[j] - mu) * rs * n1w[c0 + 8 + j] + n1b[c0 + 8 + j]);
            o2[j] = (bf16)(((float)v2[j] - mu) * rs * n1w[c0 + 16 + j] + n1b[c0 + 16 + j]);
        }
        *(bf16x8*)rp = o0; *(bf16x8*)(rp + 8) = o1; *(bf16x8*)(rp + 16) = o2;
    }
    __syncthreads();

    // ---- LN1'd token fragments (dual-use A/B)
    bf16x8 afrag[3][4];
#pragma unroll
    for (int s = 0; s < 3; ++s)
#pragma unroll
        for (int tt = 0; tt < 4; ++tt)
            afrag[s][tt] = *(const bf16x8*)&RB[(tt * 16 + q16) * LDA + s * 32 + g * 8];
    __syncthreads();   // LN1'd LDS dead; RB becomes K

    // ---- Q (M-split swapped): C[qdim][own tokens] -> bq frags (12 regs)
    bf16x8 bq[3];
    {
        int uq[6][2];
#pragma unroll
        for (int nt = 0; nt < 6; ++nt) {
            f32x4 qa = {0, 0, 0, 0};
#pragma unroll
            for (int s = 0; s < 3; ++s)
                qa = mfma16(*(const bf16x8*)(qkvT + (nt * 16 + q16) * 96 + s * 32 + g * 8),
                            afrag[s][wave], qa);
            f32x4 qb = *(const f32x4*)(qkvb + nt * 16 + g * 4);
            uq[nt][0] = pkbf(qa[0] + qb[0], qa[1] + qb[1]);
            uq[nt][1] = pkbf(qa[2] + qb[2], qa[3] + qb[3]);
        }
#pragma unroll
        for (int h = 0; h < 3; ++h)
            bq[h] = xp(uq[2 * h][0], uq[2 * h][1], uq[2 * h + 1][0], uq[2 * h + 1][1],
                       addr0, addr1, hi5);
    }

    // ---- K,V (N-split, 3 tiles/wave): K -> RB[tok][kdim], V^T -> RV
#pragma unroll 1
    for (int i = 0; i < 3; ++i) {
        const int nt = 6 + wave + i * 4;
        const int nrow = nt * 16 + q16;
        f32x4 acc[4] = {{0,0,0,0},{0,0,0,0},{0,0,0,0},{0,0,0,0}};
#pragma unroll
        for (int s = 0; s < 3; ++s) {
            bf16x8 bf = *(const bf16x8*)(qkvT + nrow * 96 + s * 32 + g * 8);
#pragma unroll
            for (int m = 0; m < 4; ++m) acc[m] = mfma16(afrag[s][m], bf, acc[m]);
        }
        float bias = qkvb[nrow];
        if (nt < 12) {
#pragma unroll
            for (int m = 0; m < 4; ++m)
#pragma unroll
                for (int r = 0; r < 4; ++r)
                    RB[(m * 16 + g * 4 + r) * LDA + (nt - 6) * 16 + q16] =
                        (bf16)(acc[m][r] + bias);
        } else {
#pragma unroll
            for (int m = 0; m < 4; ++m)
#pragma unroll
                for (int r = 0; r < 4; ++r)
                    RV[((nt - 12) * 16 + q16) * LDV + m * 16 + g * 4 + r] =
                        (bf16)(acc[m][r] + bias);
        }
    }
    __syncthreads();   // K (RB), V^T (RV) ready

    // ---- attention: swapped QK^T; P and O in registers
    const float sc_l2e = 0.17677669529663688f * 1.4426950408889634f;
    f32x4 oacc[3][2];
#pragma unroll
    for (int h = 0; h < 3; ++h) {
        f32x4 s4s[4];
#pragma unroll
        for (int kt = 0; kt < 4; ++kt) {
            bf16x8 ak = *(const bf16x8*)&RB[(kt * 16 + q16) * LDA + h * 32 + g * 8];
            f32x4 z = {0, 0, 0, 0};
            s4s[kt] = mfma16(ak, bq[h], z);
        }
        float m0 = -1e30f;
#pragma unroll
        for (int kt = 0; kt < 3; ++kt)
#pragma unroll
            for (int r = 0; r < 4; ++r) m0 = fmaxf(m0, s4s[kt][r]);
        m0 = fmaxf(m0, (g == 0) ? s4s[3][0] : -1e30f);
        m0 = fmaxf(m0, __shfl_xor(m0, 16));
        m0 = fmaxf(m0, __shfl_xor(m0, 32));
        float ss = 0.f;
#pragma unroll
        for (int kt = 0; kt < 3; ++kt)
#pragma unroll
            for (int r = 0; r < 4; ++r) {
                float e = exp2f((s4s[kt][r] - m0) * sc_l2e);
                s4s[kt][r] = e; ss += e;
            }
        {
            float e = (g == 0) ? exp2f((s4s[3][0] - m0) * sc_l2e) : 0.f;
            s4s[3][0] = e; ss += e;
            s4s[3][1] = 0.f; s4s[3][2] = 0.f; s4s[3][3] = 0.f;
        }
        ss += __shfl_xor(ss, 16);
        ss += __shfl_xor(ss, 32);
        float inv = rcpf(ss);

        int u[4][2];
#pragma unroll
        for (int kt = 0; kt < 4; ++kt) {
            u[kt][0] = pkbf(s4s[kt][0], s4s[kt][1]);
            u[kt][1] = pkbf(s4s[kt][2], s4s[kt][3]);
        }
        bf16x8 ap0 = xp(u[0][0], u[0][1], u[1][0], u[1][1], addr0, addr1, hi5);
        bf16x8 ap1 = xp(u[2][0], u[2][1], u[3][0], u[3][1], addr0, addr1, hi5);
#pragma unroll
        for (int n2 = 0; n2 < 2; ++n2) {
            int d0 = (h * 32 + n2 * 16 + q16) * LDV;
            f32x4 oa = {0, 0, 0, 0};
            oa = mfma16(*(const bf16x8*)&RV[d0 + g * 8], ap0, oa);
            oa = mfma16(*(const bf16x8*)&RV[d0 + 32 + g * 8], ap1, oa);
#pragma unroll
            for (int r = 0; r < 4; ++r) oa[r] *= inv;
            oacc[h][n2] = oa;
        }
    }
    __syncthreads();   // all K/V reads done; RB, RV reusable

    // ---- proj (M-split swapped) + shortcut; LN2 in regs; t2 -> RV
    bf16x8 bt2n[3];
    {
        int uo[3][2][2];
#pragma unroll
        for (int h = 0; h < 3; ++h)
#pragma unroll
            for (int n2 = 0; n2 < 2; ++n2) {
                uo[h][n2][0] = pkbf(oacc[h][n2][0], oacc[h][n2][1]);
                uo[h][n2][1] = pkbf(oacc[h][n2][2], oacc[h][n2][3]);
            }
        bf16x8 aoM[3];
#pragma unroll
        for (int s = 0; s < 3; ++s)
            aoM[s] = xp(uo[s][0][0], uo[s][0][1], uo[s][1][0], uo[s][1][1],
                        addr0, addr1, hi5);
        const int tok = wave * 16 + q16;
        float t2f[6][4];
#pragma unroll
        for (int nt = 0; nt < 6; ++nt) {
            f32x4 pa = {0, 0, 0, 0};
#pragma unroll
            for (int s = 0; s < 3; ++s)
                pa = mfma16(*(const bf16x8*)(projT + (nt * 16 + q16) * 96 + s * 32 + g * 8),
                            aoM[s], pa);
            f32x4 pb = *(const f32x4*)(projb + nt * 16 + g * 4);
            bf16x4 rv = *(const bf16x4*)(myWin + tok * 96 + nt * 16 + g * 4);
#pragma unroll
            for (int r = 0; r < 4; ++r) t2f[nt][r] = pa[r] + pb[r] + (float)rv[r];
        }
        // LN2 in registers
        float s = 0.f, s2 = 0.f;
#pragma unroll
        for (int nt = 0; nt < 6; ++nt)
#pragma unroll
            for (int r = 0; r < 4; ++r) { float v = t2f[nt][r]; s += v; s2 += v * v; }
        s += __shfl_xor(s, 16);  s2 += __shfl_xor(s2, 16);
        s += __shfl_xor(s, 32);  s2 += __shfl_xor(s2, 32);
        float mu = s * (1.f / 96.f);
        float rs = rsqrtf(fmaxf(s2 * (1.f / 96.f) - mu * mu, 0.f) + 1e-5f);
        int u3[6][2];
#pragma unroll
        for (int nt = 0; nt < 6; ++nt) {
            f32x4 nw = *(const f32x4*)(n2w + nt * 16 + g * 4);
            f32x4 nb = *(const f32x4*)(n2b + nt * 16 + g * 4);
            float tn0 = (t2f[nt][0] - mu) * rs * nw[0] + nb[0];
            float tn1 = (t2f[nt][1] - mu) * rs * nw[1] + nb[1];
            float tn2 = (t2f[nt][2] - mu) * rs * nw[2] + nb[2];
            float tn3 = (t2f[nt][3] - mu) * rs * nw[3] + nb[3];
            u3[nt][0] = pkbf(tn0, tn1);
            u3[nt][1] = pkbf(tn2, tn3);
            // park raw t2 (bf16-packed) in RV (dead V^T region)
            i32x2 pr = {pkbf(t2f[nt][0], t2f[nt][1]), pkbf(t2f[nt][2], t2f[nt][3])};
            *(i32x2*)&RV[tok * LDA + nt * 16 + g * 4] = pr;
        }
#pragma unroll
        for (int s5 = 0; s5 < 3; ++s5)
            bt2n[s5] = xp(u3[2 * s5][0], u3[2 * s5][1], u3[2 * s5 + 1][0], u3[2 * s5 + 1][1],
                          addr0, addr1, hi5);
    }

    // ---- MLP fully in registers: 6 chunks of 64 hidden (no barriers)
    f32x4 facc[6] = {{0,0,0,0},{0,0,0,0},{0,0,0,0},{0,0,0,0},{0,0,0,0},{0,0,0,0}};
#pragma unroll 1
    for (int ch = 0; ch < 6; ++ch) {
        int u4[4][2];
#pragma unroll
        for (int t4 = 0; t4 < 4; ++t4) {
            f32x4 ha = {0, 0, 0, 0};
#pragma unroll
            for (int s = 0; s < 3; ++s)
                ha = mfma16(*(const bf16x8*)(fc1T + (ch * 64 + t4 * 16 + q16) * 96
                                             + s * 32 + g * 8),
                            bt2n[s], ha);
            f32x4 hb = *(const f32x4*)(fc1b + ch * 64 + t4 * 16 + g * 4);
            float hg0 = gelu_f(ha[0] + hb[0]);
            float hg1 = gelu_f(ha[1] + hb[1]);
            float hg2 = gelu_f(ha[2] + hb[2]);
            float hg3 = gelu_f(ha[3] + hb[3]);
            u4[t4][0] = pkbf(hg0, hg1);
            u4[t4][1] = pkbf(hg2, hg3);
        }
        bf16x8 bh0 = xp(u4[0][0], u4[0][1], u4[1][0], u4[1][1], addr0, addr1, hi5);
        bf16x8 bh1 = xp(u4[2][0], u4[2][1], u4[3][0], u4[3][1], addr0, addr1, hi5);
#pragma unroll
        for (int nt = 0; nt < 6; ++nt) {
            facc[nt] = mfma16(*(const bf16x8*)(fc2T + (nt * 16 + q16) * 384
                                               + ch * 64 + g * 8), bh0, facc[nt]);
            facc[nt] = mfma16(*(const bf16x8*)(fc2T + (nt * 16 + q16) * 384
                                               + ch * 64 + 32 + g * 8), bh1, facc[nt]);
        }
    }

    // ---- final: out = raw t2 (RV) + fc2 + bias -> RB (own tokens, i32x2)
    {
        const int tok = wave * 16 + q16;
#pragma unroll
        for (int nt = 0; nt < 6; ++nt) {
            f32x4 fb = *(const f32x4*)(fc2b + nt * 16 + g * 4);
            i32x2 t2p = *(const i32x2*)&RV[tok * LDA + nt * 16 + g * 4];
            float v0 = facc[nt][0] + fb[0] + bf2f(t2p[0], 0);
            float v1 = facc[nt][1] + fb[1] + bf2f(t2p[0], 1);
            float v2 = facc[nt][2] + fb[2] + bf2f(t2p[1], 0);
            float v3 = facc[nt][3] + fb[3] + bf2f(t2p[1], 1);
            i32x2 po = {pkbf(v0, v1), pkbf(v2, v3)};
            *(i32x2*)&RB[tok * LDA + nt * 16 + g * 4] = po;
        }
    }
    __syncthreads();

    // ---- store (rows 0..48) -> tokW
#pragma unroll
    for (int i = 0; i < 3; ++i) {
        int id = i * 256 + tid;
        if (id < 588) {
            int row = id / 12, c8 = id - row * 12;
            *(i32x4*)(myWin + row * 96 + c8 * 8) = *(const i32x4*)&RB[row * LDA + c8 * 8];
        }
    }
}

// =============== K2 SAFE: r5 kernel verbatim (tiny-ws fallback) =============
__device__ __forceinline__ bf16x8 bload(const bf16* T, const float* worig,
                                        int nrow, int k0, int K, int N, bool wok) {
    if (wok) return *(const bf16x8*)(T + (size_t)nrow * K + k0);
    bf16x8 f;
#pragma unroll
    for (int j = 0; j < 8; ++j) f[j] = (bf16)worig[(size_t)(k0 + j) * N + nrow];
    return f;
}

__global__ __launch_bounds__(256, 4)
void swin_fused_safe(const float* __restrict__ x, bf16* __restrict__ tokW,
                const float* __restrict__ n1w, const float* __restrict__ n1b,
                const float* __restrict__ qkvw, const float* __restrict__ qkvb,
                const float* __restrict__ projw, const float* __restrict__ projb,
                const float* __restrict__ n2w, const float* __restrict__ n2b,
                const float* __restrict__ fc1w, const float* __restrict__ fc1b,
                const float* __restrict__ fc2w, const float* __restrict__ fc2b,
                const bf16* __restrict__ wsT,
                float* __restrict__ out, int fast_i, int wok_i) {
    __shared__ __attribute__((aligned(16))) bf16 L[20224];
    bf16* RB = L;
    bf16* RC = L + 6656;
    bf16* RV = L + 13312;

    const bool fast = fast_i != 0;
    const bool wok  = wok_i != 0;

    const int tid  = threadIdx.x;
    const int wave = tid >> 6;
    const int lane = tid & 63;
    const int g    = lane >> 4;
    const int q16  = lane & 15;

    const int win = blockIdx.x;
    const int b  = win >> 10;
    const int wy = (win >> 5) & 31;
    const int wx = win & 31;
    const int h0 = wy * 7, w0 = wx * 7;
    const size_t xbase = (size_t)b * 4816896;
    const bf16* myWin = tokW + (size_t)win * TOKW;

    if (fast) {
#pragma unroll
        for (int i = 0; i < 3; ++i) {
            int id = i * 256 + tid;
            int row = id / 12, c8 = id - row * 12;
            *(i32x4*)&RB[row * LDA + c8 * 8] = *(const i32x4*)(myWin + row * 96 + c8 * 8);
        }
    } else {
        for (int i = 0; i < 24; ++i) {
            int id = i * 256 + tid;
            if (id < 4704) {
                int c = id / 49, pix = id - c * 49;
                int ty = pix / 7, tx = pix - ty * 7;
                RB[pix * LDA + c] =
                    (bf16)x[xbase + (size_t)c * 50176 + (h0 + ty) * 224 + w0 + tx];
            } else if (id < 6144) {
                int j = id - 4704;
                int row = 49 + j / 96, c = j - (j / 96) * 96;
                RB[row * LDA + c] = (bf16)0.f;
            }
        }
    }
    __syncthreads();

    {
        int r = tid >> 2, p = tid & 3;
        const int c0 = p * 24;
        bf16* rp = &RB[r * LDA + c0];
        bf16x8 v0 = *(const bf16x8*)rp;
        bf16x8 v1 = *(const bf16x8*)(rp + 8);
        bf16x8 v2 = *(const bf16x8*)(rp + 16);
        float s = 0.f, s2 = 0.f;
#pragma unroll
        for (int j = 0; j < 8; ++j) {
            float a = (float)v0[j], c = (float)v1[j], d = (float)v2[j];
            s += a + c + d; s2 += a * a + c * c + d * d;
        }
        s += __shfl_xor(s, 1);  s2 += __shfl_xor(s2, 1);
        s += __shfl_xor(s, 2);  s2 += __shfl_xor(s2, 2);
        float mu = s * (1.f / 96.f);
        float rs = rsqrtf(fmaxf(s2 * (1.f / 96.f) - mu * mu, 0.f) + 1e-5f);
        bf16x8 o0, o1, o2;
#pragma unroll
        for (int j = 0; j < 8; ++j) {
            o0[j] = (bf16)(((float)v0[j] - mu) * rs * n1w[c0 + j] + n1b[c0 + j]);
            o1[j] = (bf16)(((float)v1[j] - mu) * rs * n1w[c0 + 8 + j] + n1b[c0 + 8 + j]);
            o2[j] = (bf16)(((float)v2[j] - mu) * rs * n1w[c0 + 16 + j] + n1b[c0 + 16 + j]);
        }
        *(bf16x8*)rp = o0; *(bf16x8*)(rp + 8) = o1; *(bf16x8*)(rp + 16) = o2;
    }
    __syncthreads();

    bf16x8 afrag[3][4];
#pragma unroll
    for (int s = 0; s < 3; ++s)
#pragma unroll
        for (int m = 0; m < 4; ++m)
            afrag[s][m] = *(const bf16x8*)&RB[(m * 16 + q16) * LDA + s * 32 + g * 8];
    __syncthreads();

    const bf16* qkvT  = wsT;
    const bf16* projT = wsT + 27648;
    const bf16* fc1T  = wsT + 36864;
    const bf16* fc2T  = wsT + 73728;

    for (int nt = wave; nt < 18; nt += 4) {
        const int nrow = nt * 16 + q16;
        f32x4 acc[4] = {{0,0,0,0},{0,0,0,0},{0,0,0,0},{0,0,0,0}};
#pragma unroll
        for (int s = 0; s < 3; ++s) {
            bf16x8 bf = bload(qkvT, qkvw, nrow, s * 32 + g * 8, 96, 288, wok);
#pragma unroll
            for (int m = 0; m < 4; ++m) acc[m] = mfma16(afrag[s][m], bf, acc[m]);
        }
        float bias = qkvb[nrow];
#pragma unroll
        for (int m = 0; m < 4; ++m)
#pragma unroll
            for (int r = 0; r < 4; ++r) {
                float v = acc[m][r] + bias;
                int row = m * 16 + g * 4 + r;
                bf16 hv = (bf16)v;
                if (nrow < 96)        RB[row * LDA + nrow] = hv;
                else if (nrow < 192)  RC[row * LDA + (nrow - 96)] = hv;
                else                  RV[(nrow - 192) * LDV + row] = hv;
            }
    }
    __syncthreads();

    const float sc_l2e = 0.17677669529663688f * 1.4426950408889634f;
    const bool hi5 = (lane & 32) != 0;
    const int addr0 = ((lane & 16) << 3) | (q16 << 2);
    const int addr1 = addr0 + 64;
    f32x4 oacc[3][2];
#pragma unroll
    for (int h = 0; h < 3; ++h) {
        bf16x8 bqv = *(const bf16x8*)&RB[(wave * 16 + q16) * LDA + h * 32 + g * 8];
        f32x4 s4s[4];
#pragma unroll
        for (int kt = 0; kt < 4; ++kt) {
            bf16x8 ak = *(const bf16x8*)&RC[(kt * 16 + q16) * LDA + h * 32 + g * 8];
            f32x4 z = {0, 0, 0, 0};
            s4s[kt] = mfma16(ak, bqv, z);
        }
        float m0 = -1e30f;
#pragma unroll
        for (int kt = 0; kt < 3; ++kt)
#pragma unroll
            for (int r = 0; r < 4; ++r) m0 = fmaxf(m0, s4s[kt][r]);
        m0 = fmaxf(m0, (g == 0) ? s4s[3][0] : -1e30f);
        m0 = fmaxf(m0, __shfl_xor(m0, 16));
        m0 = fmaxf(m0, __shfl_xor(m0, 32));
        float ss = 0.f;
#pragma unroll
        for (int kt = 0; kt < 3; ++kt)
#pragma unroll
            for (int r = 0; r < 4; ++r) {
                float e = exp2f((s4s[kt][r] - m0) * sc_l2e);
                s4s[kt][r] = e; ss += e;
            }
        {
            float e = (g == 0) ? exp2f((s4s[3][0] - m0) * sc_l2e) : 0.f;
            s4s[3][0] = e; ss += e;
            s4s[3][1] = 0.f; s4s[3][2] = 0.f; s4s[3][3] = 0.f;
        }
        ss += __shfl_xor(ss, 16);
        ss += __shfl_xor(ss, 32);
        float inv = rcpf(ss);

        int u[4][2];
#pragma unroll
        for (int kt = 0; kt < 4; ++kt) {
            u[kt][0] = pkbf(s4s[kt][0], s4s[kt][1]);
            u[kt][1] = pkbf(s4s[kt][2], s4s[kt][3]);
        }
        bf16x8 ap0 = xp(u[0][0], u[0][1], u[1][0], u[1][1], addr0, addr1, hi5);
        bf16x8 ap1 = xp(u[2][0], u[2][1], u[3][0], u[3][1], addr0, addr1, hi5);
#pragma unroll
        for (int n2 = 0; n2 < 2; ++n2) {
            int d0 = (h * 32 + n2 * 16 + q16) * LDV;
            f32x4 oa = {0, 0, 0, 0};
            oa = mfma16(*(const bf16x8*)&RV[d0 + g * 8], ap0, oa);
            oa = mfma16(*(const bf16x8*)&RV[d0 + 32 + g * 8], ap1, oa);
#pragma unroll
            for (int r = 0; r < 4; ++r) oa[r] *= inv;
            oacc[h][n2] = oa;
        }
    }
    __syncthreads();

    {
        int u2[3][2][2];
#pragma unroll
        for (int h = 0; h < 3; ++h)
#pragma unroll
            for (int n2 = 0; n2 < 2; ++n2) {
                u2[h][n2][0] = pkbf(oacc[h][n2][0], oacc[h][n2][1]);
                u2[h][n2][1] = pkbf(oacc[h][n2][2], oacc[h][n2][3]);
            }
        bf16x8 aoM[3];
#pragma unroll
        for (int s = 0; s < 3; ++s)
            aoM[s] = xp(u2[s][0][0], u2[s][0][1], u2[s][1][0], u2[s][1][1],
                        addr0, addr1, hi5);
#pragma unroll
        for (int nt = 0; nt < 6; ++nt) {
            int nrow = nt * 16 + q16;
            f32x4 pacc = {0, 0, 0, 0};
#pragma unroll
            for (int s = 0; s < 3; ++s) {
                bf16x8 bf = bload(projT, projw, nrow, s * 32 + g * 8, 96, 96, wok);
                pacc = mfma16(aoM[s], bf, pacc);
            }
            float bias = projb[nrow];
#pragma unroll
            for (int r = 0; r < 4; ++r) {
                int row = wave * 16 + g * 4 + r;
                float sc;
                if (fast) sc = (float)myWin[row * 96 + nrow];
                else      sc = (row < 49)
                    ? x[xbase + (size_t)nrow * 50176 + (h0 + row / 7) * 224 + w0 + row % 7]
                    : 0.f;
                RV[row * LDA + nrow] = (bf16)(pacc[r] + bias + sc);
            }
        }
    }
    __syncthreads();

    {
        int r = tid >> 2, p = tid & 3;
        const int c0 = p * 24;
        const bf16* rp = &RV[r * LDA + c0];
        bf16x8 v0 = *(const bf16x8*)rp;
        bf16x8 v1 = *(const bf16x8*)(rp + 8);
        bf16x8 v2 = *(const bf16x8*)(rp + 16);
        float s = 0.f, s2 = 0.f;
#pragma unroll
        for (int j = 0; j < 8; ++j) {
            float a = (float)v0[j], c = (float)v1[j], d = (float)v2[j];
            s += a + c + d; s2 += a * a + c * c + d * d;
        }
        s += __shfl_xor(s, 1);  s2 += __shfl_xor(s2, 1);
        s += __shfl_xor(s, 2);  s2 += __shfl_xor(s2, 2);
        float mu = s * (1.f / 96.f);
        float rs = rsqrtf(fmaxf(s2 * (1.f / 96.f) - mu * mu, 0.f) + 1e-5f);
        bf16x8 o0, o1, o2;
#pragma unroll
        for (int j = 0; j < 8; ++j) {
            o0[j] = (bf16)(((float)v0[j] - mu) * rs * n2w[c0 + j] + n2b[c0 + j]);
            o1[j] = (bf16)(((float)v1[j] - mu) * rs * n2w[c0 + 8 + j] + n2b[c0 + 8 + j]);
            o2[j] = (bf16)(((float)v2[j] - mu) * rs * n2w[c0 + 16 + j] + n2b[c0 + 16 + j]);
        }
        bf16* wp = &RB[r * LDA + c0];
        *(bf16x8*)wp = o0; *(bf16x8*)(wp + 8) = o1; *(bf16x8*)(wp + 16) = o2;
    }
    __syncthreads();

    const int npt = (wave < 2) ? 2 : 1;
    f32x4 f2acc[2][4] = {{{0,0,0,0},{0,0,0,0},{0,0,0,0},{0,0,0,0}},
                         {{0,0,0,0},{0,0,0,0},{0,0,0,0},{0,0,0,0}}};
    for (int ch = 0; ch < 4; ++ch) {
#pragma unroll
        for (int t = 0; t < 2; ++t) {
            if (t < npt) {
                int ntl = (t == 0) ? wave : wave + 4;
                int nrow = (ch * 6 + ntl) * 16 + q16;
                f32x4 acc[4] = {{0,0,0,0},{0,0,0,0},{0,0,0,0},{0,0,0,0}};
#pragma unroll
                for (int s = 0; s < 3; ++s) {
                    bf16x8 bf = bload(fc1T, fc1w, nrow, s * 32 + g * 8, 96, 384, wok);
#pragma unroll
                    for (int m = 0; m < 4; ++m) {
                        bf16x8 a = *(const bf16x8*)&RB[(m * 16 + q16) * LDA + s * 32 + g * 8];
                        acc[m] = mfma16(a, bf, acc[m]);
                    }
                }
                float bias = fc1b[nrow];
#pragma unroll
                for (int m = 0; m < 4; ++m)
#pragma unroll
                    for (int r = 0; r < 4; ++r)
                        RC[(m * 16 + g * 4 + r) * LDA + ntl * 16 + q16] =
                            (bf16)gelu_f(acc[m][r] + bias);
            }
        }
        __syncthreads();
#pragma unroll
        for (int s = 0; s < 3; ++s) {
            bf16x8 a0 = *(const bf16x8*)&RC[(q16)      * LDA + s * 32 + g * 8];
            bf16x8 a1 = *(const bf16x8*)&RC[(16 + q16) * LDA + s * 32 + g * 8];
            bf16x8 a2 = *(const bf16x8*)&RC[(32 + q16) * LDA + s * 32 + g * 8];
            bf16x8 a3 = *(const bf16x8*)&RC[(48 + q16) * LDA + s * 32 + g * 8];
#pragma unroll
            for (int t = 0; t < 2; ++t) {
                if (t < npt) {
                    int nt = (t == 0) ? wave : wave + 4;
                    int nrow = nt * 16 + q16;
                    bf16x8 bf = bload(fc2T, fc2w, nrow, ch * 96 + s * 32 + g * 8, 384, 96, wok);
                    f2acc[t][0] = mfma16(a0, bf, f2acc[t][0]);
                    f2acc[t][1] = mfma16(a1, bf, f2acc[t][1]);
                    f2acc[t][2] = mfma16(a2, bf, f2acc[t][2]);
                    f2acc[t][3] = mfma16(a3, bf, f2acc[t][3]);
                }
            }
        }
        __syncthreads();
    }

#pragma unroll
    for (int t = 0; t < 2; ++t) {
        if (t < npt) {
            int col = ((t == 0) ? wave : wave + 4) * 16 + q16;
            float bias = fc2b[col];
#pragma unroll
            for (int m = 0; m < 4; ++m)
#pragma unroll
                for (int r = 0; r < 4; ++r) {
                    int row = m * 16 + g * 4 + r;
                    float t2 = (float)RV[row * LDA + col];
                    RV[row * LDA + col] = (bf16)(f2acc[t][m][r] + bias + t2);
                }
        }
    }
    __syncthreads();

    if (fast) {
#pragma unroll
        for (int i = 0; i < 3; ++i) {
            int id = i * 256 + tid;
            if (id < 588) {
                int row = id / 12, c8 = id - row * 12;
                *(i32x4*)(tokW + (size_t)win * TOKW + row * 96 + c8 * 8) =
                    *(const i32x4*)&RV[row * LDA + c8 * 8];
            }
        }
    } else {
        for (int i = 0; i < 19; ++i) {
            int id = i * 256 + tid;
            if (id < 4704) {
                int c = id / 49, pix = id - c * 49;
                int ty = pix / 7, tx = pix - ty * 7;
                out[xbase + (size_t)c * 50176 + (h0 + ty) * 224 + w0 + tx] =
                    (float)RV[pix * LDA + c];
            }
        }
    }
}

// ---------------------------------------------------------------------------
extern "C" void kernel_launch(void* const* d_in, const int* in_sizes, int n_in,
                              void* d_out, int out_size, void* d_ws, size_t ws_size,
                              hipStream_t stream) {
    const float* x      = (const float*)d_in[0];
    const float* n1w    = (const float*)d_in[1];
    const float* n1b    = (const float*)d_in[2];
    const float* qkv_w  = (const float*)d_in[3];
    const float* qkv_b  = (const float*)d_in[4];
    const float* proj_w = (const float*)d_in[5];
    const float* proj_b = (const float*)d_in[6];
    const float* n2w    = (const float*)d_in[7];
    const float* n2b    = (const float*)d_in[8];
    const float* fc1_w  = (const float*)d_in[9];
    const float* fc1_b  = (const float*)d_in[10];
    const float* fc2_w  = (const float*)d_in[11];
    const float* fc2_b  = (const float*)d_in[12];
    float* out = (float*)d_out;

    const size_t TOKW_OFF = 225280;
    const int wok  = (ws_size >= 221184) ? 1 : 0;
    const int fast = (ws_size >= TOKW_OFF + 100663296ull) ? 1 : 0;
    bf16* wsT  = (bf16*)d_ws;
    bf16* tokW = (bf16*)((char*)d_ws + TOKW_OFF);

    if (wok)
        swin_wprep<<<dim3(432), dim3(256), 0, stream>>>(qkv_w, proj_w, fc1_w, fc2_w, wsT);
    if (fast) {
        swin_padfill<<<dim3(5760), dim3(256), 0, stream>>>(tokW);
        swin_gather<<<dim3(1792), dim3(256), 0, stream>>>(x, tokW);
    }
    if (fast && wok) {
        swin_fused_fast<<<dim3(8192), dim3(256), 0, stream>>>(
            tokW, n1w, n1b, qkv_b, proj_b, n2w, n2b, fc1_b, fc2_b, wsT);
    } else {
        swin_fused_safe<<<dim3(8192), dim3(256), 0, stream>>>(
            x, tokW, n1w, n1b, qkv_w, qkv_b, proj_w, proj_b, n2w, n2b,
            fc1_w, fc1_b, fc2_w, fc2_b, wsT, out, fast, wok);
    }
    if (fast)
        swin_scatter<<<dim3(1792), dim3(256), 0, stream>>>(tokW, out);
}

// Round 9
// 391.554 us; speedup vs baseline: 1.8165x; 1.8165x over previous
//
#include <hip/hip_runtime.h>

// ---------------------------------------------------------------------------
// SwinTransformerBlock, MI355X / gfx950. fp32 I/O, bf16 MFMA core.
// wprep -> padfill -> gather -> fused (per 7x7 window) -> scatter.
// Round 9: r5 structure (proven clean, 389us) + b128-only weight loads in
//   the hot kernel (fallback isolated in a separate kernel) + balanced
//   6x64-chunk MLP (1 fc1 tile/wave). No in-register MLP (spill-proven).
// ---------------------------------------------------------------------------

typedef __bf16 bf16;
typedef __attribute__((ext_vector_type(8))) __bf16 bf16x8;
typedef __attribute__((ext_vector_type(4))) float f32x4;
typedef __attribute__((ext_vector_type(4))) int i32x4;

#define LDA 104      // row stride (elems) for [64][*] LDS tiles
#define LDV 72       // row stride for V^T [96][*]
#define LDW 233      // gather/scatter transpose-tile stride
#define TOKW 6144    // 64*96 elems per window

union U8 { int i[4]; bf16x8 v; };

__device__ __forceinline__ f32x4 mfma16(bf16x8 a, bf16x8 b, f32x4 c) {
    return __builtin_amdgcn_mfma_f32_16x16x32_bf16(a, b, c, 0, 0, 0);
}
__device__ __forceinline__ int pkbf(float lo, float hi) {
    int r; asm("v_cvt_pk_bf16_f32 %0, %1, %2" : "=v"(r) : "v"(lo), "v"(hi)); return r;
}
__device__ __forceinline__ float rcpf(float x) {
    float r; asm("v_rcp_f32 %0, %1" : "=v"(r) : "v"(x)); return r;
}
__device__ __forceinline__ float gelu_f(float v) {
    const float a = -2.30220770f, b = -0.10294852f;
    float e = exp2f(v * __builtin_fmaf(b, v * v, a));
    return v * rcpf(1.f + e);
}

// 16x32 C-tile -> fragment transpose (verified r3-r8).
__device__ __forceinline__ bf16x8 xp(int p0, int p1, int q0, int q1,
                                     int addr0, int addr1, bool hi5) {
    U8 w;
    int a0 = __builtin_amdgcn_ds_bpermute(addr0, p0);
    int b0 = __builtin_amdgcn_ds_bpermute(addr0, q0);
    w.i[0] = hi5 ? b0 : a0;
    int a1 = __builtin_amdgcn_ds_bpermute(addr0, p1);
    int b1 = __builtin_amdgcn_ds_bpermute(addr0, q1);
    w.i[1] = hi5 ? b1 : a1;
    int a2 = __builtin_amdgcn_ds_bpermute(addr1, p0);
    int b2 = __builtin_amdgcn_ds_bpermute(addr1, q0);
    w.i[2] = hi5 ? b2 : a2;
    int a3 = __builtin_amdgcn_ds_bpermute(addr1, p1);
    int b3 = __builtin_amdgcn_ds_bpermute(addr1, q1);
    w.i[3] = hi5 ? b3 : a3;
    return w.v;
}

// ---------------- weight pre-transpose (fp32 -> bf16 [N][K]) ---------------
__global__ void swin_wprep(const float* __restrict__ qkv_w,
                           const float* __restrict__ proj_w,
                           const float* __restrict__ fc1_w,
                           const float* __restrict__ fc2_w,
                           bf16* __restrict__ wsT) {
    int i = blockIdx.x * 256 + threadIdx.x;
    if (i < 27648) { int n = i / 96, k = i - n * 96; wsT[i] = (bf16)qkv_w[k * 288 + n]; }
    else if (i < 36864) { int j = i - 27648, n = j / 96, k = j - n * 96; wsT[i] = (bf16)proj_w[k * 96 + n]; }
    else if (i < 73728) { int j = i - 36864, n = j / 96, k = j - n * 96; wsT[i] = (bf16)fc1_w[k * 384 + n]; }
    else if (i < 110592){ int j = i - 73728, n = j / 384, k = j - n * 384; wsT[i] = (bf16)fc2_w[k * 96 + n]; }
}

// ---------------- K0: zero pad rows 49..63 of every window -----------------
__global__ void swin_padfill(bf16* __restrict__ tokW) {
    int id = blockIdx.x * 256 + threadIdx.x;
    int win = id / 180, r = id - win * 180;
    int row = 49 + r / 12, c8 = r - (r / 12) * 12;
    *(i32x4*)(tokW + (size_t)win * TOKW + row * 96 + c8 * 8) = i32x4{0, 0, 0, 0};
}

// ---------------- K1: x[B,C,H,W] fp32 -> tokW[win][64][96] bf16 ------------
__global__ __launch_bounds__(256)
void swin_gather(const float* __restrict__ x, bf16* __restrict__ tokW) {
    __shared__ bf16 sT[96 * LDW];
    const int tid = threadIdx.x;
    const int bi = blockIdx.x;
    const int b = bi / 224, h = bi - b * 224;
    const int wy = h / 7, ty = h - wy * 7;
    const size_t xbase = (size_t)b * 4816896 + (size_t)h * 224;

#pragma unroll
    for (int i = 0; i < 21; ++i) {
        int id = i * 256 + tid;
        int c = id / 56, w4 = id - c * 56;
        f32x4 v = *(const f32x4*)(x + xbase + (size_t)c * 50176 + w4 * 4);
#pragma unroll
        for (int j = 0; j < 4; ++j) sT[c * LDW + w4 * 4 + j] = (bf16)v[j];
    }
    __syncthreads();

#pragma unroll
    for (int i = 0; i < 11; ++i) {
        int id = i * 256 + tid;
        if (id < 2688) {
            int win = id / 84, r = id - win * 84;
            int tx = r / 12, c8 = r - tx * 12;
            bf16x8 v;
#pragma unroll
            for (int j = 0; j < 8; ++j) v[j] = sT[(c8 * 8 + j) * LDW + win * 7 + tx];
            *(i32x4*)(tokW + (size_t)(b * 1024 + wy * 32 + win) * TOKW
                      + (ty * 7 + tx) * 96 + c8 * 8) = *(i32x4*)&v;
        }
    }
}

// ---------------- K3: tokW -> out[B,C,H,W] fp32 ----------------------------
__global__ __launch_bounds__(256)
void swin_scatter(const bf16* __restrict__ tokW, float* __restrict__ out) {
    __shared__ bf16 sT[96 * LDW];
    const int tid = threadIdx.x;
    const int bi = blockIdx.x;
    const int b = bi / 224, h = bi - b * 224;
    const int wy = h / 7, ty = h - wy * 7;
    const size_t obase = (size_t)b * 4816896 + (size_t)h * 224;

#pragma unroll
    for (int i = 0; i < 11; ++i) {
        int id = i * 256 + tid;
        if (id < 2688) {
            int win = id / 84, r = id - win * 84;
            int tx = r / 12, c8 = r - tx * 12;
            bf16x8 v = *(const bf16x8*)(tokW + (size_t)(b * 1024 + wy * 32 + win) * TOKW
                                        + (ty * 7 + tx) * 96 + c8 * 8);
#pragma unroll
            for (int j = 0; j < 8; ++j) sT[(c8 * 8 + j) * LDW + win * 7 + tx] = v[j];
        }
    }
    __syncthreads();

#pragma unroll
    for (int i = 0; i < 21; ++i) {
        int id = i * 256 + tid;
        int c = id / 56, w4 = id - c * 56;
        f32x4 v;
#pragma unroll
        for (int j = 0; j < 4; ++j) v[j] = (float)sT[c * LDW + w4 * 4 + j];
        *(f32x4*)(out + obase + (size_t)c * 50176 + w4 * 4) = v;
    }
}

// =============== K2 FAST: r5 structure, b128-only weights ===================
__global__ __launch_bounds__(256, 4)
void swin_fused_fast(bf16* __restrict__ tokW,
                     const float* __restrict__ n1w, const float* __restrict__ n1b,
                     const float* __restrict__ qkvb, const float* __restrict__ projb,
                     const float* __restrict__ n2w, const float* __restrict__ n2b,
                     const float* __restrict__ fc1b, const float* __restrict__ fc2b,
                     const bf16* __restrict__ wsT) {
    // 40448 B -> 4 blocks/CU
    __shared__ __attribute__((aligned(16))) bf16 L[20224];
    bf16* RB = L;              // raw -> LN1'd -> Q -> LN2'd t2
    bf16* RC = L + 6656;       // K -> hidden chunks
    bf16* RV = L + 13312;      // V^T [96][LDV] -> raw t2 [64][LDA] -> final

    const int tid  = threadIdx.x;
    const int wave = tid >> 6;
    const int lane = tid & 63;
    const int g    = lane >> 4;
    const int q16  = lane & 15;

    const int win = blockIdx.x;
    bf16* myWin = tokW + (size_t)win * TOKW;

    const bf16* qkvT  = wsT;
    const bf16* projT = wsT + 27648;
    const bf16* fc1T  = wsT + 36864;
    const bf16* fc2T  = wsT + 73728;

    // ---- P0: window -> RB (raw tokens; pad rows pre-zeroed in tokW)
#pragma unroll
    for (int i = 0; i < 3; ++i) {
        int id = i * 256 + tid;
        int row = id / 12, c8 = id - row * 12;
        *(i32x4*)&RB[row * LDA + c8 * 8] = *(const i32x4*)(myWin + row * 96 + c8 * 8);
    }
    __syncthreads();

    // ---- LN1: stats + normalize in place (4 lanes per row)
    {
        int r = tid >> 2, p = tid & 3;
        const int c0 = p * 24;
        bf16* rp = &RB[r * LDA + c0];
        bf16x8 v0 = *(const bf16x8*)rp;
        bf16x8 v1 = *(const bf16x8*)(rp + 8);
        bf16x8 v2 = *(const bf16x8*)(rp + 16);
        float s = 0.f, s2 = 0.f;
#pragma unroll
        for (int j = 0; j < 8; ++j) {
            float a = (float)v0[j], c = (float)v1[j], d = (float)v2[j];
            s += a + c + d; s2 += a * a + c * c + d * d;
        }
        s += __shfl_xor(s, 1);  s2 += __shfl_xor(s2, 1);
        s += __shfl_xor(s, 2);  s2 += __shfl_xor(s2, 2);
        float mu = s * (1.f / 96.f);
        float rs = rsqrtf(fmaxf(s2 * (1.f / 96.f) - mu * mu, 0.f) + 1e-5f);
        bf16x8 o0, o1, o2;
#pragma unroll
        for (int j = 0; j < 8; ++j) {
            o0[j] = (bf16)(((float)v0[j] - mu) * rs * n1w[c0 + j] + n1b[c0 + j]);
            o1[j] = (bf16)(((float)v1[j] - mu) * rs * n1w[c0 + 8 + j] + n1b[c0 + 8 + j]);
            o2[j] = (bf16)(((float)v2[j] - mu) * rs * n1w[c0 + 16 + j] + n1b[c0 + 16 + j]);
        }
        *(bf16x8*)rp = o0; *(bf16x8*)(rp + 8) = o1; *(bf16x8*)(rp + 16) = o2;
    }
    __syncthreads();

    // ---- LN1'd token fragments (held only through QKV)
    bf16x8 afrag[3][4];
#pragma unroll
    for (int s = 0; s < 3; ++s)
#pragma unroll
        for (int m = 0; m < 4; ++m)
            afrag[s][m] = *(const bf16x8*)&RB[(m * 16 + q16) * LDA + s * 32 + g * 8];
    __syncthreads();   // all LN1'd reads done; RB reusable for Q

    // ---- QKV GEMM (N-split across waves)
    for (int nt = wave; nt < 18; nt += 4) {
        const int nrow = nt * 16 + q16;
        f32x4 acc[4] = {{0,0,0,0},{0,0,0,0},{0,0,0,0},{0,0,0,0}};
#pragma unroll
        for (int s = 0; s < 3; ++s) {
            bf16x8 bf = *(const bf16x8*)(qkvT + (size_t)nrow * 96 + s * 32 + g * 8);
#pragma unroll
            for (int m = 0; m < 4; ++m) acc[m] = mfma16(afrag[s][m], bf, acc[m]);
        }
        float bias = qkvb[nrow];
#pragma unroll
        for (int m = 0; m < 4; ++m)
#pragma unroll
            for (int r = 0; r < 4; ++r) {
                float v = acc[m][r] + bias;
                int row = m * 16 + g * 4 + r;
                bf16 hv = (bf16)v;
                if (nrow < 96)        RB[row * LDA + nrow] = hv;              // Q
                else if (nrow < 192)  RC[row * LDA + (nrow - 96)] = hv;       // K
                else                  RV[(nrow - 192) * LDV + row] = hv;      // V^T
            }
    }
    __syncthreads();   // Q/K/V ready

    // ---- attention: swapped QK^T; P and O in registers
    const float sc_l2e = 0.17677669529663688f * 1.4426950408889634f;
    const bool hi5 = (lane & 32) != 0;
    const int addr0 = ((lane & 16) << 3) | (q16 << 2);
    const int addr1 = addr0 + 64;
    f32x4 oacc[3][2];
#pragma unroll
    for (int h = 0; h < 3; ++h) {
        bf16x8 bq = *(const bf16x8*)&RB[(wave * 16 + q16) * LDA + h * 32 + g * 8];
        f32x4 s4s[4];
#pragma unroll
        for (int kt = 0; kt < 4; ++kt) {
            bf16x8 ak = *(const bf16x8*)&RC[(kt * 16 + q16) * LDA + h * 32 + g * 8];
            f32x4 z = {0, 0, 0, 0};
            s4s[kt] = mfma16(ak, bq, z);   // S^T[key kt*16+g*4+r][q q16]
        }
        float m0 = -1e30f;
#pragma unroll
        for (int kt = 0; kt < 3; ++kt)
#pragma unroll
            for (int r = 0; r < 4; ++r) m0 = fmaxf(m0, s4s[kt][r]);
        m0 = fmaxf(m0, (g == 0) ? s4s[3][0] : -1e30f);
        m0 = fmaxf(m0, __shfl_xor(m0, 16));
        m0 = fmaxf(m0, __shfl_xor(m0, 32));
        float ss = 0.f;
#pragma unroll
        for (int kt = 0; kt < 3; ++kt)
#pragma unroll
            for (int r = 0; r < 4; ++r) {
                float e = exp2f((s4s[kt][r] - m0) * sc_l2e);
                s4s[kt][r] = e; ss += e;
            }
        {
            float e = (g == 0) ? exp2f((s4s[3][0] - m0) * sc_l2e) : 0.f;
            s4s[3][0] = e; ss += e;
            s4s[3][1] = 0.f; s4s[3][2] = 0.f; s4s[3][3] = 0.f;
        }
        ss += __shfl_xor(ss, 16);
        ss += __shfl_xor(ss, 32);
        float inv = rcpf(ss);

        int u[4][2];
#pragma unroll
        for (int kt = 0; kt < 4; ++kt) {
            u[kt][0] = pkbf(s4s[kt][0], s4s[kt][1]);
            u[kt][1] = pkbf(s4s[kt][2], s4s[kt][3]);
        }
        bf16x8 ap0 = xp(u[0][0], u[0][1], u[1][0], u[1][1], addr0, addr1, hi5);
        bf16x8 ap1 = xp(u[2][0], u[2][1], u[3][0], u[3][1], addr0, addr1, hi5);
#pragma unroll
        for (int n2 = 0; n2 < 2; ++n2) {
            int d0 = (h * 32 + n2 * 16 + q16) * LDV;
            f32x4 oa = {0, 0, 0, 0};
            oa = mfma16(*(const bf16x8*)&RV[d0 + g * 8], ap0, oa);
            oa = mfma16(*(const bf16x8*)&RV[d0 + 32 + g * 8], ap1, oa);
#pragma unroll
            for (int r = 0; r < 4; ++r) oa[r] *= inv;
            oacc[h][n2] = oa;
        }
    }
    __syncthreads();   // all V^T reads done; RV reusable for raw t2

    // ---- proj (M-split swapped); raw t2 -> RV
    {
        int u2[3][2][2];
#pragma unroll
        for (int h = 0; h < 3; ++h)
#pragma unroll
            for (int n2 = 0; n2 < 2; ++n2) {
                u2[h][n2][0] = pkbf(oacc[h][n2][0], oacc[h][n2][1]);
                u2[h][n2][1] = pkbf(oacc[h][n2][2], oacc[h][n2][3]);
            }
        bf16x8 aoM[3];
#pragma unroll
        for (int s = 0; s < 3; ++s)
            aoM[s] = xp(u2[s][0][0], u2[s][0][1], u2[s][1][0], u2[s][1][1],
                        addr0, addr1, hi5);
#pragma unroll
        for (int nt = 0; nt < 6; ++nt) {
            int nrow = nt * 16 + q16;
            f32x4 pacc = {0, 0, 0, 0};
#pragma unroll
            for (int s = 0; s < 3; ++s) {
                bf16x8 bf = *(const bf16x8*)(projT + (size_t)nrow * 96 + s * 32 + g * 8);
                pacc = mfma16(aoM[s], bf, pacc);
            }
            float bias = projb[nrow];
#pragma unroll
            for (int r = 0; r < 4; ++r) {
                int row = wave * 16 + g * 4 + r;
                float sc = (float)myWin[row * 96 + nrow];
                RV[row * LDA + nrow] = (bf16)(pacc[r] + bias + sc);   // raw t2
            }
        }
    }
    __syncthreads();

    // ---- LN2: stats + normalize, RV (raw t2) -> RB (LN2'd)
    {
        int r = tid >> 2, p = tid & 3;
        const int c0 = p * 24;
        const bf16* rp = &RV[r * LDA + c0];
        bf16x8 v0 = *(const bf16x8*)rp;
        bf16x8 v1 = *(const bf16x8*)(rp + 8);
        bf16x8 v2 = *(const bf16x8*)(rp + 16);
        float s = 0.f, s2 = 0.f;
#pragma unroll
        for (int j = 0; j < 8; ++j) {
            float a = (float)v0[j], c = (float)v1[j], d = (float)v2[j];
            s += a + c + d; s2 += a * a + c * c + d * d;
        }
        s += __shfl_xor(s, 1);  s2 += __shfl_xor(s2, 1);
        s += __shfl_xor(s, 2);  s2 += __shfl_xor(s2, 2);
        float mu = s * (1.f / 96.f);
        float rs = rsqrtf(fmaxf(s2 * (1.f / 96.f) - mu * mu, 0.f) + 1e-5f);
        bf16x8 o0, o1, o2;
#pragma unroll
        for (int j = 0; j < 8; ++j) {
            o0[j] = (bf16)(((float)v0[j] - mu) * rs * n2w[c0 + j] + n2b[c0 + j]);
            o1[j] = (bf16)(((float)v1[j] - mu) * rs * n2w[c0 + 8 + j] + n2b[c0 + 8 + j]);
            o2[j] = (bf16)(((float)v2[j] - mu) * rs * n2w[c0 + 16 + j] + n2b[c0 + 16 + j]);
        }
        bf16* wp = &RB[r * LDA + c0];
        *(bf16x8*)wp = o0; *(bf16x8*)(wp + 8) = o1; *(bf16x8*)(wp + 16) = o2;
    }
    __syncthreads();

    // ---- MLP: 6 chunks of 64 hidden; fc1 balanced 1 tile/wave
    const int npt = (wave < 2) ? 2 : 1;
    f32x4 f2acc[2][4] = {{{0,0,0,0},{0,0,0,0},{0,0,0,0},{0,0,0,0}},
                         {{0,0,0,0},{0,0,0,0},{0,0,0,0},{0,0,0,0}}};
    for (int ch = 0; ch < 6; ++ch) {
        // fc1: my hid tile (cols wave*16.. of this chunk) -> GELU -> RC
        {
            const int hrow = ch * 64 + wave * 16 + q16;
            f32x4 acc[4] = {{0,0,0,0},{0,0,0,0},{0,0,0,0},{0,0,0,0}};
#pragma unroll
            for (int s = 0; s < 3; ++s) {
                bf16x8 bf = *(const bf16x8*)(fc1T + (size_t)hrow * 96 + s * 32 + g * 8);
#pragma unroll
                for (int m = 0; m < 4; ++m) {
                    bf16x8 a = *(const bf16x8*)&RB[(m * 16 + q16) * LDA + s * 32 + g * 8];
                    acc[m] = mfma16(a, bf, acc[m]);
                }
            }
            float bias = fc1b[hrow];
#pragma unroll
            for (int m = 0; m < 4; ++m)
#pragma unroll
                for (int r = 0; r < 4; ++r)
                    RC[(m * 16 + g * 4 + r) * LDA + wave * 16 + q16] =
                        (bf16)gelu_f(acc[m][r] + bias);
        }
        __syncthreads();
        // fc2: partial-K over this chunk's 64 hidden; a-frags shared across tiles
#pragma unroll
        for (int ks = 0; ks < 2; ++ks) {
            bf16x8 a0 = *(const bf16x8*)&RC[(q16)      * LDA + ks * 32 + g * 8];
            bf16x8 a1 = *(const bf16x8*)&RC[(16 + q16) * LDA + ks * 32 + g * 8];
            bf16x8 a2 = *(const bf16x8*)&RC[(32 + q16) * LDA + ks * 32 + g * 8];
            bf16x8 a3 = *(const bf16x8*)&RC[(48 + q16) * LDA + ks * 32 + g * 8];
#pragma unroll
            for (int t = 0; t < 2; ++t) {
                if (t < npt) {
                    int ot = (t == 0) ? wave : wave + 4;
                    bf16x8 bf = *(const bf16x8*)(fc2T + (size_t)(ot * 16 + q16) * 384
                                                 + ch * 64 + ks * 32 + g * 8);
                    f2acc[t][0] = mfma16(a0, bf, f2acc[t][0]);
                    f2acc[t][1] = mfma16(a1, bf, f2acc[t][1]);
                    f2acc[t][2] = mfma16(a2, bf, f2acc[t][2]);
                    f2acc[t][3] = mfma16(a3, bf, f2acc[t][3]);
                }
            }
        }
        __syncthreads();
    }

    // ---- final: out = raw t2 (RV) + fc2 + bias -> RV in place
#pragma unroll
    for (int t = 0; t < 2; ++t) {
        if (t < npt) {
            int col = ((t == 0) ? wave : wave + 4) * 16 + q16;
            float bias = fc2b[col];
#pragma unroll
            for (int m = 0; m < 4; ++m)
#pragma unroll
                for (int r = 0; r < 4; ++r) {
                    int row = m * 16 + g * 4 + r;
                    float t2 = (float)RV[row * LDA + col];
                    RV[row * LDA + col] = (bf16)(f2acc[t][m][r] + bias + t2);
                }
        }
    }
    __syncthreads();

    // ---- store (rows 0..48) -> tokW
#pragma unroll
    for (int i = 0; i < 3; ++i) {
        int id = i * 256 + tid;
        if (id < 588) {
            int row = id / 12, c8 = id - row * 12;
            *(i32x4*)(myWin + row * 96 + c8 * 8) = *(const i32x4*)&RV[row * LDA + c8 * 8];
        }
    }
}

// =============== K2 SAFE: r5 kernel verbatim (tiny-ws fallback) =============
__device__ __forceinline__ bf16x8 bload(const bf16* T, const float* worig,
                                        int nrow, int k0, int K, int N, bool wok) {
    if (wok) return *(const bf16x8*)(T + (size_t)nrow * K + k0);
    bf16x8 f;
#pragma unroll
    for (int j = 0; j < 8; ++j) f[j] = (bf16)worig[(size_t)(k0 + j) * N + nrow];
    return f;
}

__global__ __launch_bounds__(256, 4)
void swin_fused_safe(const float* __restrict__ x, bf16* __restrict__ tokW,
                const float* __restrict__ n1w, const float* __restrict__ n1b,
                const float* __restrict__ qkvw, const float* __restrict__ qkvb,
                const float* __restrict__ projw, const float* __restrict__ projb,
                const float* __restrict__ n2w, const float* __restrict__ n2b,
                const float* __restrict__ fc1w, const float* __restrict__ fc1b,
                const float* __restrict__ fc2w, const float* __restrict__ fc2b,
                const bf16* __restrict__ wsT,
                float* __restrict__ out, int fast_i, int wok_i) {
    __shared__ __attribute__((aligned(16))) bf16 L[20224];
    bf16* RB = L;
    bf16* RC = L + 6656;
    bf16* RV = L + 13312;

    const bool fast = fast_i != 0;
    const bool wok  = wok_i != 0;

    const int tid  = threadIdx.x;
    const int wave = tid >> 6;
    const int lane = tid & 63;
    const int g    = lane >> 4;
    const int q16  = lane & 15;

    const int win = blockIdx.x;
    const int b  = win >> 10;
    const int wy = (win >> 5) & 31;
    const int wx = win & 31;
    const int h0 = wy * 7, w0 = wx * 7;
    const size_t xbase = (size_t)b * 4816896;
    const bf16* myWin = tokW + (size_t)win * TOKW;

    if (fast) {
#pragma unroll
        for (int i = 0; i < 3; ++i) {
            int id = i * 256 + tid;
            int row = id / 12, c8 = id - row * 12;
            *(i32x4*)&RB[row * LDA + c8 * 8] = *(const i32x4*)(myWin + row * 96 + c8 * 8);
        }
    } else {
        for (int i = 0; i < 24; ++i) {
            int id = i * 256 + tid;
            if (id < 4704) {
                int c = id / 49, pix = id - c * 49;
                int ty = pix / 7, tx = pix - ty * 7;
                RB[pix * LDA + c] =
                    (bf16)x[xbase + (size_t)c * 50176 + (h0 + ty) * 224 + w0 + tx];
            } else if (id < 6144) {
                int j = id - 4704;
                int row = 49 + j / 96, c = j - (j / 96) * 96;
                RB[row * LDA + c] = (bf16)0.f;
            }
        }
    }
    __syncthreads();

    {
        int r = tid >> 2, p = tid & 3;
        const int c0 = p * 24;
        bf16* rp = &RB[r * LDA + c0];
        bf16x8 v0 = *(const bf16x8*)rp;
        bf16x8 v1 = *(const bf16x8*)(rp + 8);
        bf16x8 v2 = *(const bf16x8*)(rp + 16);
        float s = 0.f, s2 = 0.f;
#pragma unroll
        for (int j = 0; j < 8; ++j) {
            float a = (float)v0[j], c = (float)v1[j], d = (float)v2[j];
            s += a + c + d; s2 += a * a + c * c + d * d;
        }
        s += __shfl_xor(s, 1);  s2 += __shfl_xor(s2, 1);
        s += __shfl_xor(s, 2);  s2 += __shfl_xor(s2, 2);
        float mu = s * (1.f / 96.f);
        float rs = rsqrtf(fmaxf(s2 * (1.f / 96.f) - mu * mu, 0.f) + 1e-5f);
        bf16x8 o0, o1, o2;
#pragma unroll
        for (int j = 0; j < 8; ++j) {
            o0[j] = (bf16)(((float)v0[j] - mu) * rs * n1w[c0 + j] + n1b[c0 + j]);
            o1[j] = (bf16)(((float)v1[j] - mu) * rs * n1w[c0 + 8 + j] + n1b[c0 + 8 + j]);
            o2[j] = (bf16)(((float)v2[j] - mu) * rs * n1w[c0 + 16 + j] + n1b[c0 + 16 + j]);
        }
        *(bf16x8*)rp = o0; *(bf16x8*)(rp + 8) = o1; *(bf16x8*)(rp + 16) = o2;
    }
    __syncthreads();

    bf16x8 afrag[3][4];
#pragma unroll
    for (int s = 0; s < 3; ++s)
#pragma unroll
        for (int m = 0; m < 4; ++m)
            afrag[s][m] = *(const bf16x8*)&RB[(m * 16 + q16) * LDA + s * 32 + g * 8];
    __syncthreads();

    const bf16* qkvT  = wsT;
    const bf16* projT = wsT + 27648;
    const bf16* fc1T  = wsT + 36864;
    const bf16* fc2T  = wsT + 73728;

    for (int nt = wave; nt < 18; nt += 4) {
        const int nrow = nt * 16 + q16;
        f32x4 acc[4] = {{0,0,0,0},{0,0,0,0},{0,0,0,0},{0,0,0,0}};
#pragma unroll
        for (int s = 0; s < 3; ++s) {
            bf16x8 bf = bload(qkvT, qkvw, nrow, s * 32 + g * 8, 96, 288, wok);
#pragma unroll
            for (int m = 0; m < 4; ++m) acc[m] = mfma16(afrag[s][m], bf, acc[m]);
        }
        float bias = qkvb[nrow];
#pragma unroll
        for (int m = 0; m < 4; ++m)
#pragma unroll
            for (int r = 0; r < 4; ++r) {
                float v = acc[m][r] + bias;
                int row = m * 16 + g * 4 + r;
                bf16 hv = (bf16)v;
                if (nrow < 96)        RB[row * LDA + nrow] = hv;
                else if (nrow < 192)  RC[row * LDA + (nrow - 96)] = hv;
                else                  RV[(nrow - 192) * LDV + row] = hv;
            }
    }
    __syncthreads();

    const float sc_l2e = 0.17677669529663688f * 1.4426950408889634f;
    const bool hi5 = (lane & 32) != 0;
    const int addr0 = ((lane & 16) << 3) | (q16 << 2);
    const int addr1 = addr0 + 64;
    f32x4 oacc[3][2];
#pragma unroll
    for (int h = 0; h < 3; ++h) {
        bf16x8 bqv = *(const bf16x8*)&RB[(wave * 16 + q16) * LDA + h * 32 + g * 8];
        f32x4 s4s[4];
#pragma unroll
        for (int kt = 0; kt < 4; ++kt) {
            bf16x8 ak = *(const bf16x8*)&RC[(kt * 16 + q16) * LDA + h * 32 + g * 8];
            f32x4 z = {0, 0, 0, 0};
            s4s[kt] = mfma16(ak, bqv, z);
        }
        float m0 = -1e30f;
#pragma unroll
        for (int kt = 0; kt < 3; ++kt)
#pragma unroll
            for (int r = 0; r < 4; ++r) m0 = fmaxf(m0, s4s[kt][r]);
        m0 = fmaxf(m0, (g == 0) ? s4s[3][0] : -1e30f);
        m0 = fmaxf(m0, __shfl_xor(m0, 16));
        m0 = fmaxf(m0, __shfl_xor(m0, 32));
        float ss = 0.f;
#pragma unroll
        for (int kt = 0; kt < 3; ++kt)
#pragma unroll
            for (int r = 0; r < 4; ++r) {
                float e = exp2f((s4s[kt][r] - m0) * sc_l2e);
                s4s[kt][r] = e; ss += e;
            }
        {
            float e = (g == 0) ? exp2f((s4s[3][0] - m0) * sc_l2e) : 0.f;
            s4s[3][0] = e; ss += e;
            s4s[3][1] = 0.f; s4s[3][2] = 0.f; s4s[3][3] = 0.f;
        }
        ss += __shfl_xor(ss, 16);
        ss += __shfl_xor(ss, 32);
        float inv = rcpf(ss);

        int u[4][2];
#pragma unroll
        for (int kt = 0; kt < 4; ++kt) {
            u[kt][0] = pkbf(s4s[kt][0], s4s[kt][1]);
            u[kt][1] = pkbf(s4s[kt][2], s4s[kt][3]);
        }
        bf16x8 ap0 = xp(u[0][0], u[0][1], u[1][0], u[1][1], addr0, addr1, hi5);
        bf16x8 ap1 = xp(u[2][0], u[2][1], u[3][0], u[3][1], addr0, addr1, hi5);
#pragma unroll
        for (int n2 = 0; n2 < 2; ++n2) {
            int d0 = (h * 32 + n2 * 16 + q16) * LDV;
            f32x4 oa = {0, 0, 0, 0};
            oa = mfma16(*(const bf16x8*)&RV[d0 + g * 8], ap0, oa);
            oa = mfma16(*(const bf16x8*)&RV[d0 + 32 + g * 8], ap1, oa);
#pragma unroll
            for (int r = 0; r < 4; ++r) oa[r] *= inv;
            oacc[h][n2] = oa;
        }
    }
    __syncthreads();

    {
        int u2[3][2][2];
#pragma unroll
        for (int h = 0; h < 3; ++h)
#pragma unroll
            for (int n2 = 0; n2 < 2; ++n2) {
                u2[h][n2][0] = pkbf(oacc[h][n2][0], oacc[h][n2][1]);
                u2[h][n2][1] = pkbf(oacc[h][n2][2], oacc[h][n2][3]);
            }
        bf16x8 aoM[3];
#pragma unroll
        for (int s = 0; s < 3; ++s)
            aoM[s] = xp(u2[s][0][0], u2[s][0][1], u2[s][1][0], u2[s][1][1],
                        addr0, addr1, hi5);
#pragma unroll
        for (int nt = 0; nt < 6; ++nt) {
            int nrow = nt * 16 + q16;
            f32x4 pacc = {0, 0, 0, 0};
#pragma unroll
            for (int s = 0; s < 3; ++s) {
                bf16x8 bf = bload(projT, projw, nrow, s * 32 + g * 8, 96, 96, wok);
                pacc = mfma16(aoM[s], bf, pacc);
            }
            float bias = projb[nrow];
#pragma unroll
            for (int r = 0; r < 4; ++r) {
                int row = wave * 16 + g * 4 + r;
                float sc;
                if (fast) sc = (float)myWin[row * 96 + nrow];
                else      sc = (row < 49)
                    ? x[xbase + (size_t)nrow * 50176 + (h0 + row / 7) * 224 + w0 + row % 7]
                    : 0.f;
                RV[row * LDA + nrow] = (bf16)(pacc[r] + bias + sc);
            }
        }
    }
    __syncthreads();

    {
        int r = tid >> 2, p = tid & 3;
        const int c0 = p * 24;
        const bf16* rp = &RV[r * LDA + c0];
        bf16x8 v0 = *(const bf16x8*)rp;
        bf16x8 v1 = *(const bf16x8*)(rp + 8);
        bf16x8 v2 = *(const bf16x8*)(rp + 16);
        float s = 0.f, s2 = 0.f;
#pragma unroll
        for (int j = 0; j < 8; ++j) {
            float a = (float)v0[j], c = (float)v1[j], d = (float)v2[j];
            s += a + c + d; s2 += a * a + c * c + d * d;
        }
        s += __shfl_xor(s, 1);  s2 += __shfl_xor(s2, 1);
        s += __shfl_xor(s, 2);  s2 += __shfl_xor(s2, 2);
        float mu = s * (1.f / 96.f);
        float rs = rsqrtf(fmaxf(s2 * (1.f / 96.f) - mu * mu, 0.f) + 1e-5f);
        bf16x8 o0, o1, o2;
#pragma unroll
        for (int j = 0; j < 8; ++j) {
            o0[j] = (bf16)(((float)v0[j] - mu) * rs * n2w[c0 + j] + n2b[c0 + j]);
            o1[j] = (bf16)(((float)v1[j] - mu) * rs * n2w[c0 + 8 + j] + n2b[c0 + 8 + j]);
            o2[j] = (bf16)(((float)v2[j] - mu) * rs * n2w[c0 + 16 + j] + n2b[c0 + 16 + j]);
        }
        bf16* wp = &RB[r * LDA + c0];
        *(bf16x8*)wp = o0; *(bf16x8*)(wp + 8) = o1; *(bf16x8*)(wp + 16) = o2;
    }
    __syncthreads();

    const int npt = (wave < 2) ? 2 : 1;
    f32x4 f2acc[2][4] = {{{0,0,0,0},{0,0,0,0},{0,0,0,0},{0,0,0,0}},
                         {{0,0,0,0},{0,0,0,0},{0,0,0,0},{0,0,0,0}}};
    for (int ch = 0; ch < 4; ++ch) {
#pragma unroll
        for (int t = 0; t < 2; ++t) {
            if (t < npt) {
                int ntl = (t == 0) ? wave : wave + 4;
                int nrow = (ch * 6 + ntl) * 16 + q16;
                f32x4 acc[4] = {{0,0,0,0},{0,0,0,0},{0,0,0,0},{0,0,0,0}};
#pragma unroll
                for (int s = 0; s < 3; ++s) {
                    bf16x8 bf = bload(fc1T, fc1w, nrow, s * 32 + g * 8, 96, 384, wok);
#pragma unroll
                    for (int m = 0; m < 4; ++m) {
                        bf16x8 a = *(const bf16x8*)&RB[(m * 16 + q16) * LDA + s * 32 + g * 8];
                        acc[m] = mfma16(a, bf, acc[m]);
                    }
                }
                float bias = fc1b[nrow];
#pragma unroll
                for (int m = 0; m < 4; ++m)
#pragma unroll
                    for (int r = 0; r < 4; ++r)
                        RC[(m * 16 + g * 4 + r) * LDA + ntl * 16 + q16] =
                            (bf16)gelu_f(acc[m][r] + bias);
            }
        }
        __syncthreads();
#pragma unroll
        for (int s = 0; s < 3; ++s) {
            bf16x8 a0 = *(const bf16x8*)&RC[(q16)      * LDA + s * 32 + g * 8];
            bf16x8 a1 = *(const bf16x8*)&RC[(16 + q16) * LDA + s * 32 + g * 8];
            bf16x8 a2 = *(const bf16x8*)&RC[(32 + q16) * LDA + s * 32 + g * 8];
            bf16x8 a3 = *(const bf16x8*)&RC[(48 + q16) * LDA + s * 32 + g * 8];
#pragma unroll
            for (int t = 0; t < 2; ++t) {
                if (t < npt) {
                    int nt = (t == 0) ? wave : wave + 4;
                    int nrow = nt * 16 + q16;
                    bf16x8 bf = bload(fc2T, fc2w, nrow, ch * 96 + s * 32 + g * 8, 384, 96, wok);
                    f2acc[t][0] = mfma16(a0, bf, f2acc[t][0]);
                    f2acc[t][1] = mfma16(a1, bf, f2acc[t][1]);
                    f2acc[t][2] = mfma16(a2, bf, f2acc[t][2]);
                    f2acc[t][3] = mfma16(a3, bf, f2acc[t][3]);
                }
            }
        }
        __syncthreads();
    }

#pragma unroll
    for (int t = 0; t < 2; ++t) {
        if (t < npt) {
            int col = ((t == 0) ? wave : wave + 4) * 16 + q16;
            float bias = fc2b[col];
#pragma unroll
            for (int m = 0; m < 4; ++m)
#pragma unroll
                for (int r = 0; r < 4; ++r) {
                    int row = m * 16 + g * 4 + r;
                    float t2 = (float)RV[row * LDA + col];
                    RV[row * LDA + col] = (bf16)(f2acc[t][m][r] + bias + t2);
                }
        }
    }
    __syncthreads();

    if (fast) {
#pragma unroll
        for (int i = 0; i < 3; ++i) {
            int id = i * 256 + tid;
            if (id < 588) {
                int row = id / 12, c8 = id - row * 12;
                *(i32x4*)(tokW + (size_t)win * TOKW + row * 96 + c8 * 8) =
                    *(const i32x4*)&RV[row * LDA + c8 * 8];
            }
        }
    } else {
        for (int i = 0; i < 19; ++i) {
            int id = i * 256 + tid;
            if (id < 4704) {
                int c = id / 49, pix = id - c * 49;
                int ty = pix / 7, tx = pix - ty * 7;
                out[xbase + (size_t)c * 50176 + (h0 + ty) * 224 + w0 + tx] =
                    (float)RV[pix * LDA + c];
            }
        }
    }
}

// ---------------------------------------------------------------------------
extern "C" void kernel_launch(void* const* d_in, const int* in_sizes, int n_in,
                              void* d_out, int out_size, void* d_ws, size_t ws_size,
                              hipStream_t stream) {
    const float* x      = (const float*)d_in[0];
    const float* n1w    = (const float*)d_in[1];
    const float* n1b    = (const float*)d_in[2];
    const float* qkv_w  = (const float*)d_in[3];
    const float* qkv_b  = (const float*)d_in[4];
    const float* proj_w = (const float*)d_in[5];
    const float* proj_b = (const float*)d_in[6];
    const float* n2w    = (const float*)d_in[7];
    const float* n2b    = (const float*)d_in[8];
    const float* fc1_w  = (const float*)d_in[9];
    const float* fc1_b  = (const float*)d_in[10];
    const float* fc2_w  = (const float*)d_in[11];
    const float* fc2_b  = (const float*)d_in[12];
    float* out = (float*)d_out;

    const size_t TOKW_OFF = 225280;
    const int wok  = (ws_size >= 221184) ? 1 : 0;
    const int fast = (ws_size >= TOKW_OFF + 100663296ull) ? 1 : 0;
    bf16* wsT  = (bf16*)d_ws;
    bf16* tokW = (bf16*)((char*)d_ws + TOKW_OFF);

    if (wok)
        swin_wprep<<<dim3(432), dim3(256), 0, stream>>>(qkv_w, proj_w, fc1_w, fc2_w, wsT);
    if (fast) {
        swin_padfill<<<dim3(5760), dim3(256), 0, stream>>>(tokW);
        swin_gather<<<dim3(1792), dim3(256), 0, stream>>>(x, tokW);
    }
    if (fast && wok) {
        swin_fused_fast<<<dim3(8192), dim3(256), 0, stream>>>(
            tokW, n1w, n1b, qkv_b, proj_b, n2w, n2b, fc1_b, fc2_b, wsT);
    } else {
        swin_fused_safe<<<dim3(8192), dim3(256), 0, stream>>>(
            x, tokW, n1w, n1b, qkv_w, qkv_b, proj_w, proj_b, n2w, n2b,
            fc1_w, fc1_b, fc2_w, fc2_b, wsT, out, fast, wok);
    }
    if (fast)
        swin_scatter<<<dim3(1792), dim3(256), 0, stream>>>(tokW, out);
}